// Round 5
// baseline (590.425 us; speedup 1.0000x reference)
//
#include <hip/hip_runtime.h>
#include <cstdint>
#include <cstddef>

#define H_      128
#define B_      64
#define T_      20
#define S_      10
#define L_      20
#define NITEMS  50000
#define NSEQ    704            // 64 cur + 640 frd sequences, all length 20
#define NTOK    (NSEQ * 20)    // 14080
#define NPAD    50048          // items padded to multiple of 128 for GEMM tiles
#define KA      256            // effective K of final GEMM (skip zero middle)
#define K2BLOCKS 880           // NTOK/16
#define K1BLOCKS 4171          // ceil(NPAD*32 / 384)

typedef __attribute__((ext_vector_type(8))) short short8;
typedef __attribute__((ext_vector_type(4))) float f32x4;

__device__ __forceinline__ unsigned short f2bf(float f) {
  unsigned int u = __float_as_uint(f);
  u += 0x7FFF + ((u >> 16) & 1);   // round-to-nearest-even
  return (unsigned short)(u >> 16);
}
__device__ __forceinline__ float sigmoidf_(float x) {
  return 1.0f / (1.0f + __expf(-x));
}

// ---------------------------------------------------------------------------
// K12: role-split merge of former K1 (w fp32->bf16 convert, BW-bound) and
// K2 (gi = v_emb @ W_ih^T + b_ih, VALU-bound). Independent work; merging
// removes a launch gap and overlaps HBM with VALU. Block 0 also zeroes the
// per-b completion counters used by K46's last-block fusion.
__global__ void __launch_bounds__(384) k12(const float* __restrict__ w,
                                           unsigned short* __restrict__ wb,
                                           const int* __restrict__ cur,
                                           const int* __restrict__ frd,
                                           const float* __restrict__ vemb,
                                           const float* __restrict__ Wih,
                                           const float* __restrict__ bih,
                                           float* __restrict__ gi,
                                           int* __restrict__ cnt) {
  int tid = threadIdx.x;
  if (blockIdx.x < K2BLOCKS) {
    // ---- K2 role ----
    __shared__ float xs[16 * 128];
    __shared__ int ids[16];
    if (blockIdx.x == 0 && tid < 64) cnt[tid] = 0;
    int tok0 = blockIdx.x * 16;
    if (tid < 16) {
      int tok = tok0 + tid;
      int seq = tok / 20, tt = tok % 20;
      ids[tid] = (seq < 64) ? cur[seq * 20 + tt] : frd[(seq - 64) * 20 + tt];
    }
    __syncthreads();
    for (int idx = tid; idx < 512; idx += 384) {
      int i = idx >> 5, kc = idx & 31;
      *(float4*)&xs[i * 128 + kc * 4] =
          *(const float4*)&vemb[(size_t)ids[i] * 128 + kc * 4];
    }
    __syncthreads();
    int j  = tid % 192;        // gates j and j+192
    int th = tid / 192;        // token half (wave-uniform)
    float acc0[8], acc1[8];
#pragma unroll
    for (int i = 0; i < 8; i++) { acc0[i] = 0.f; acc1[i] = 0.f; }
    const float* wr0 = Wih + (size_t)j * 128;
    const float* wr1 = Wih + (size_t)(j + 192) * 128;
    const float* xb = &xs[th * 8 * 128];
    for (int kc = 0; kc < 32; kc++) {
      float4 wa = *(const float4*)(wr0 + kc * 4);
      float4 wc = *(const float4*)(wr1 + kc * 4);
#pragma unroll
      for (int i = 0; i < 8; i++) {
        float4 x4 = *(const float4*)&xb[i * 128 + kc * 4];
        acc0[i] += wa.x * x4.x + wa.y * x4.y + wa.z * x4.z + wa.w * x4.w;
        acc1[i] += wc.x * x4.x + wc.y * x4.y + wc.z * x4.z + wc.w * x4.w;
      }
    }
    float ba = bih[j], bc = bih[j + 192];
#pragma unroll
    for (int i = 0; i < 8; i++) {
      size_t row = (size_t)(tok0 + th * 8 + i) * 384;
      gi[row + j]       = acc0[i] + ba;
      gi[row + j + 192] = acc1[i] + bc;
    }
  } else {
    // ---- K1 role: wb[n][256] bf16 from w[n][384], dropping cols 128..255 ----
    int t = (blockIdx.x - K2BLOCKS) * 384 + tid;
    if (t < NPAD * 32) {
      int n = t >> 5, kc = t & 31;
      int k0 = kc * 8;
      unsigned int o0, o1, o2, o3;
      if (n < NITEMS) {
        int src = (k0 < 128) ? k0 : (k0 + 128);
        const float* p = w + (size_t)n * 384 + src;
        float4 f0 = *(const float4*)p;
        float4 f1 = *(const float4*)(p + 4);
        o0 = (unsigned)f2bf(f0.x) | ((unsigned)f2bf(f0.y) << 16);
        o1 = (unsigned)f2bf(f0.z) | ((unsigned)f2bf(f0.w) << 16);
        o2 = (unsigned)f2bf(f1.x) | ((unsigned)f2bf(f1.y) << 16);
        o3 = (unsigned)f2bf(f1.z) | ((unsigned)f2bf(f1.w) << 16);
      } else {
        o0 = o1 = o2 = o3 = 0u;
      }
      *(uint4*)(wb + (size_t)n * 256 + k0) = make_uint4(o0, o1, o2, o3);
    }
  }
}

// ---------------------------------------------------------------------------
// K3: GRU recurrence, fp32. Thread j keeps W_hh row j (128 fp32) in registers;
// h broadcast from LDS. 3 sequences per block, G==3 statically unrolled with
// 3 independent accumulator chains (3x ILP; per-acc fp32 order unchanged).
__global__ void __launch_bounds__(384) k3_gru(const float* __restrict__ Whh,
                                              const float* __restrict__ bhh,
                                              const float* __restrict__ gi,
                                              float* __restrict__ out_h) {
  __shared__ float hb[3 * 128];
  __shared__ float pre[3 * 256];
  __shared__ float gin[3 * 128];
  __shared__ float ghn[3 * 128];
  int j = threadIdx.x;
  int seq0 = blockIdx.x * 3;
  int G = NSEQ - seq0; if (G > 3) G = 3;
  float4 wv[32];
  const float4* wr = (const float4*)(Whh + (size_t)j * 128);
#pragma unroll
  for (int kc = 0; kc < 32; kc++) wv[kc] = wr[kc];
  float bb = bhh[j];
  if (j < 128) { hb[j] = 0.f; hb[128 + j] = 0.f; hb[256 + j] = 0.f; }
  __syncthreads();
  if (G == 3) {
    for (int t = 0; t < 20; t++) {
      float a0 = bb, a1 = bb, a2 = bb;
#pragma unroll
      for (int kc = 0; kc < 32; kc++) {
        float4 w4 = wv[kc];
        float4 h0 = *(const float4*)&hb[0 * 128 + kc * 4];
        float4 h1 = *(const float4*)&hb[1 * 128 + kc * 4];
        float4 h2 = *(const float4*)&hb[2 * 128 + kc * 4];
        a0 += w4.x * h0.x + w4.y * h0.y + w4.z * h0.z + w4.w * h0.w;
        a1 += w4.x * h1.x + w4.y * h1.y + w4.z * h1.z + w4.w * h1.w;
        a2 += w4.x * h2.x + w4.y * h2.y + w4.z * h2.z + w4.w * h2.w;
      }
      float g0 = gi[(size_t)((seq0 + 0) * 20 + t) * 384 + j];
      float g1 = gi[(size_t)((seq0 + 1) * 20 + t) * 384 + j];
      float g2 = gi[(size_t)((seq0 + 2) * 20 + t) * 384 + j];
      if (j < 256) {
        pre[0 * 256 + j] = g0 + a0;
        pre[1 * 256 + j] = g1 + a1;
        pre[2 * 256 + j] = g2 + a2;
      } else {
        gin[0 * 128 + (j - 256)] = g0; ghn[0 * 128 + (j - 256)] = a0;
        gin[1 * 128 + (j - 256)] = g1; ghn[1 * 128 + (j - 256)] = a1;
        gin[2 * 128 + (j - 256)] = g2; ghn[2 * 128 + (j - 256)] = a2;
      }
      __syncthreads();
      if (j < 128) {
#pragma unroll
        for (int g = 0; g < 3; g++) {
          float r = sigmoidf_(pre[g * 256 + j]);
          float z = sigmoidf_(pre[g * 256 + 128 + j]);
          float n = tanhf(gin[g * 128 + j] + r * ghn[g * 128 + j]);
          float hN = (1.f - z) * n + z * hb[g * 128 + j];
          hb[g * 128 + j] = hN;
          out_h[(size_t)((seq0 + g) * 20 + t) * 128 + j] = hN;
        }
      }
      __syncthreads();
    }
  } else {
    for (int t = 0; t < 20; t++) {
      for (int g = 0; g < G; g++) {
        float acc = bb;
#pragma unroll
        for (int kc = 0; kc < 32; kc++) {
          float4 h4 = *(const float4*)&hb[g * 128 + kc * 4];
          float4 w4 = wv[kc];
          acc += w4.x * h4.x + w4.y * h4.y + w4.z * h4.z + w4.w * h4.w;
        }
        float gv = gi[(size_t)((seq0 + g) * 20 + t) * 384 + j];
        if (j < 256) pre[g * 256 + j] = gv + acc;
        else { gin[g * 128 + (j - 256)] = gv; ghn[g * 128 + (j - 256)] = acc; }
      }
      __syncthreads();
      if (j < 128) {
        for (int g = 0; g < G; g++) {
          float r = sigmoidf_(pre[g * 256 + j]);
          float z = sigmoidf_(pre[g * 256 + 128 + j]);
          float n = tanhf(gin[g * 128 + j] + r * ghn[g * 128 + j]);
          float hN = (1.f - z) * n + z * hb[g * 128 + j];
          hb[g * 128 + j] = hN;
          out_h[(size_t)((seq0 + g) * 20 + t) * 128 + j] = hN;
        }
      }
      __syncthreads();
    }
  }
}

// ---------------------------------------------------------------------------
// K46f: fused K4 (sim_raw) + K6 (sess_emb) per (b,s) block, PLUS last-block
// K5 chain (double masked softmax + hf + act pack) for b once all 10 s-blocks
// of that b are done (device-scope atomicAdd + __threadfence, rocPRIM-style).
__global__ void __launch_bounds__(256) k46f(const int* __restrict__ users,
                                            const int* __restrict__ frd,
                                            const float* __restrict__ vemb,
                                            const float* __restrict__ uemb,
                                            const float* __restrict__ out_h,
                                            float* __restrict__ sim_raw,
                                            float* __restrict__ sess,
                                            int* __restrict__ cnt,
                                            unsigned int* __restrict__ act) {
  __shared__ float qs[20 * 132];
  __shared__ float es[20 * 132];
  __shared__ float fs[20 * 132];
  __shared__ float sc[400];
  __shared__ float us[128];
  __shared__ float dt[20];
  __shared__ float wl[20];
  __shared__ int fid[20];
  __shared__ int lastflag;
  int tid = threadIdx.x;
  int b = blockIdx.x / 10, s = blockIdx.x % 10;
  int eseq = 64 + b * 10 + s;
  if (tid < 20) fid[tid] = frd[(size_t)(b * 10 + s) * 20 + tid];
  if (tid < 128) us[tid] = uemb[(size_t)users[b] * 128 + tid];
  __syncthreads();
  for (int idx = tid; idx < 640; idx += 256) {
    int row = idx >> 5, kc = idx & 31;
    *(float4*)&fs[row * 132 + kc * 4] =
        *(const float4*)&vemb[(size_t)fid[row] * 128 + kc * 4];
    *(float4*)&qs[row * 132 + kc * 4] =
        *(const float4*)&out_h[(size_t)(b * 20 + row) * 128 + kc * 4];
    *(float4*)&es[row * 132 + kc * 4] =
        *(const float4*)&out_h[(size_t)(eseq * 20 + row) * 128 + kc * 4];
  }
  __syncthreads();
  // k4 scores
  for (int idx = tid; idx < 400; idx += 256) {
    int t = idx / 20, l = idx % 20;
    float acc = 0.f;
#pragma unroll
    for (int kc = 0; kc < 32; kc++) {
      float4 q4 = *(const float4*)&qs[t * 132 + kc * 4];
      float4 e4 = *(const float4*)&es[l * 132 + kc * 4];
      acc += q4.x * e4.x + q4.y * e4.y + q4.z * e4.z + q4.w * e4.w;
    }
    sc[idx] = acc;
  }
  // k6 user-dot
  if (tid < 20) {
    float acc = 0.f;
    for (int kc = 0; kc < 32; kc++) {
      float4 u4 = *(const float4*)&us[kc * 4];
      float4 f4 = *(const float4*)&fs[tid * 132 + kc * 4];
      acc += u4.x * f4.x + u4.y * f4.y + u4.z * f4.z + u4.w * f4.w;
    }
    dt[tid] = acc;
  }
  __syncthreads();
  if (tid < 20) {
    float m = sc[tid * 20];
    for (int l = 1; l < 20; l++) m = fmaxf(m, sc[tid * 20 + l]);
    sim_raw[(size_t)(b * 10 + s) * 20 + tid] = m;
    float mx = -3.4e38f;
    for (int l = 0; l < 20; l++) mx = fmaxf(mx, dt[l]);
    float sum = 0.f;
    for (int l = 0; l < 20; l++) sum += __expf(dt[l] - mx);
    wl[tid] = __expf(dt[tid] - mx) / sum;
  }
  __syncthreads();
  if (tid < 128) {
    float acc = 0.f;
    for (int l = 0; l < 20; l++) acc += wl[l] * fs[l * 132 + tid];
    sess[(size_t)(b * 10 + s) * 128 + tid] = acc;
  }
  // ---- completion protocol ----
  __syncthreads();
  __threadfence();                       // release our sim_raw/sess writes
  if (tid == 0) lastflag = (atomicAdd(&cnt[b], 1) == 9);
  __syncthreads();
  if (!lastflag) return;
  __threadfence();                       // acquire other blocks' writes

  // ---- K5 chain for this b (exact former k5_fused arithmetic) ----
  // LDS reuse: sv->sc[0:200], s1->qs[0:200], sf->qs[400:600],
  // se[10*128]->es[0:1280], pres->fid[0:10]
  float* sv = sc;
  float* s1 = qs;
  float* sf = qs + 400;
  float* se = es;
  int* pres = fid;
  for (int idx = tid; idx < 200; idx += 256) sv[idx] = sim_raw[(size_t)b * 200 + idx];
  for (int idx = tid; idx < 1280; idx += 256) se[idx] = sess[(size_t)b * 1280 + idx];
  if (tid < 10) pres[tid] = 0;
  __syncthreads();
  if (tid < 20) {
    int t = tid;
    float mx = -3.4e38f;
    for (int ss = 0; ss < 10; ss++) mx = fmaxf(mx, sv[ss * 20 + t]);
    float sum = 0.f;
    for (int ss = 0; ss < 10; ss++) sum += __expf(sv[ss * 20 + t] - mx);
    float inv = 1.0f / sum;
    float v1 = -1.f, v2 = -1.f; int i1 = 0, i2 = 0;
    for (int ss = 0; ss < 10; ss++) {
      float v = __expf(sv[ss * 20 + t] - mx) * inv;
      s1[ss * 20 + t] = v;
      if (v > v1) { v2 = v1; i2 = i1; v1 = v; i1 = ss; }
      else if (v > v2) { v2 = v; i2 = ss; }
    }
    atomicOr(&pres[i1], 1);
    atomicOr(&pres[i2], 1);
  }
  __syncthreads();
  if (tid < 20) {
    int t = tid;
    float mx = -3.4e38f;
    for (int ss = 0; ss < 10; ss++) if (pres[ss]) mx = fmaxf(mx, s1[ss * 20 + t]);
    float sum = 0.f;
    for (int ss = 0; ss < 10; ss++) if (pres[ss]) sum += __expf(s1[ss * 20 + t] - mx);
    float inv = 1.f / sum;
    float mx2 = -3.4e38f;
    for (int ss = 0; ss < 10; ss++)
      if (pres[ss]) mx2 = fmaxf(mx2, __expf(s1[ss * 20 + t] - mx) * inv);
    float sum2 = 0.f;
    for (int ss = 0; ss < 10; ss++)
      if (pres[ss]) sum2 += __expf(__expf(s1[ss * 20 + t] - mx) * inv - mx2);
    float inv2 = 1.f / sum2;
    for (int ss = 0; ss < 10; ss++) {
      float o = 0.f;
      if (pres[ss]) o = __expf(__expf(s1[ss * 20 + t] - mx) * inv - mx2) * inv2;
      sf[ss * 20 + t] = o;
    }
  }
  __syncthreads();
  for (int idx = tid; idx < 2560; idx += 256) {
    int t = idx >> 7, p = idx & 127;
    int m = b * 20 + t;
    float a0, a1;
    if (p < 64) {
      a0 = out_h[(size_t)m * 128 + p * 2];
      a1 = out_h[(size_t)m * 128 + p * 2 + 1];
    } else {
      int h0 = (p - 64) * 2;
      float acc0 = 0.f, acc1 = 0.f;
#pragma unroll
      for (int ss = 0; ss < 10; ss++) {
        float w = sf[ss * 20 + t];
        acc0 += w * se[ss * 128 + h0];
        acc1 += w * se[ss * 128 + h0 + 1];
      }
      a0 = acc0; a1 = acc1;
    }
    act[(size_t)m * 128 + p] = (unsigned)f2bf(a0) | ((unsigned)f2bf(a1) << 16);
  }
}

// ---------------------------------------------------------------------------
// K9: logits[1280][50000] = act(bf16) @ wb^T + b.  [round-0 structure, now
// M-split x2]: 782 blocks; block = (col-tile, M-half). Halves the tail
// granularity of the all-resident schedule (391 blocks left half the CUs
// idle for the second half of the span). wb re-read is L3-resident.
__device__ __forceinline__ void async_cp16(const unsigned short* g, unsigned short* l) {
  __builtin_amdgcn_global_load_lds((__attribute__((address_space(1))) void*)g,
                                   (__attribute__((address_space(3))) void*)l,
                                   16, 0, 0);
}

__global__ void __launch_bounds__(256) k9_gemm(const unsigned short* __restrict__ act,
                                               const unsigned short* __restrict__ wb,
                                               const float* __restrict__ bias,
                                               float* __restrict__ out) {
  __shared__ __align__(16) unsigned short Bs[128 * 256];      // 64 KB, xor-swizzled
  __shared__ __align__(16) unsigned short As[128 * 40];       // 10 KB, padded rows (5 chunks)
  int tid = threadIdx.x;
  int w = tid >> 6, lane = tid & 63;
  int q = (lane >> 4) & 3, c = lane & 15;
  int wm = w >> 1, wn = w & 1;
  int tile = blockIdx.x >> 1, mh = blockIdx.x & 1;
  int nb0 = tile * 128;

  // stage full B tile once: rows n_l = 0..127, 32 chunks (16B) per row
#pragma unroll
  for (int i = 0; i < 16; i++) {
    int n_l = i * 8 + w * 2 + (lane >> 5);
    int p = lane & 31;
    int kc = p ^ (n_l & 31);
    async_cp16(wb + (size_t)(nb0 + n_l) * 256 + kc * 8,
               &Bs[(i * 8 + w * 2) * 256]);
  }

  // bias + bounds per nt (hoisted)
  float bs[4]; int okn[4]; int ncol[4];
#pragma unroll
  for (int nt = 0; nt < 4; nt++) {
    int n = nb0 + wn * 64 + nt * 16 + c;
    ncol[nt] = n;
    okn[nt] = (n < NITEMS);
    bs[nt] = (n < NITEMS) ? bias[n] : 0.f;
  }

  for (int mc = mh * 5; mc < mh * 5 + 5; mc++) {
    f32x4 acc[4][4];
#pragma unroll
    for (int mt = 0; mt < 4; mt++)
#pragma unroll
      for (int nt = 0; nt < 4; nt++) {
        f32x4 z = {0.f, 0.f, 0.f, 0.f};
        acc[mt][nt] = z;
      }
    for (int kf = 0; kf < 8; kf++) {
      __syncthreads();  // previous slice consumed (and B-DMA drained on 1st pass)
      // stage A slice: 128 rows x 32 k (bf16), padded to 5 chunks/row
      {
        int ch0 = tid * 2;
#pragma unroll
        for (int jj = 0; jj < 2; jj++) {
          int ch = ch0 + jj;
          int row = ch >> 2, kk = ch & 3;
          short8 v = *(const short8*)&act[(size_t)(mc * 128 + row) * 256 + kf * 32 + kk * 8];
          *(short8*)&As[row * 40 + kk * 8] = v;
        }
      }
      __syncthreads();
      short8 bfr[4];
#pragma unroll
      for (int nt = 0; nt < 4; nt++) {
        int n_l = wn * 64 + nt * 16 + c;
        int slot = n_l * 32 + ((kf * 4 + q) ^ (n_l & 31));
        bfr[nt] = *(const short8*)&Bs[slot * 8];
      }
#pragma unroll
      for (int mt = 0; mt < 4; mt++) {
        int row = wm * 64 + mt * 16 + c;
        short8 af = *(const short8*)&As[row * 40 + q * 8];
#pragma unroll
        for (int nt = 0; nt < 4; nt++)
          acc[mt][nt] = __builtin_amdgcn_mfma_f32_16x16x32_bf16(af, bfr[nt], acc[mt][nt], 0, 0, 0);
      }
    }
    // epilogue: D row = q*4+r, col = c (C/D layout: col=lane&15, row=quad*4+reg)
#pragma unroll
    for (int nt = 0; nt < 4; nt++) {
      if (okn[nt]) {
#pragma unroll
        for (int mt = 0; mt < 4; mt++) {
          int m = mc * 128 + wm * 64 + mt * 16 + q * 4;
#pragma unroll
          for (int r = 0; r < 4; r++)
            out[(size_t)(m + r) * NITEMS + ncol[nt]] = acc[mt][nt][r] + bs[nt];
        }
      }
    }
  }
}

// ---------------------------------------------------------------------------
extern "C" void kernel_launch(void* const* d_in, const int* in_sizes, int n_in,
                              void* d_out, int out_size, void* d_ws, size_t ws_size,
                              hipStream_t stream) {
  const int*   users = (const int*)d_in[0];
  const int*   cur   = (const int*)d_in[1];
  // d_in[2] = hist_sess (unused by reference)
  const int*   frd   = (const int*)d_in[3];
  // d_in[4] = cur_sess_len (unused by reference)
  const float* vemb  = (const float*)d_in[5];
  const float* uemb  = (const float*)d_in[6];
  const float* Wih   = (const float*)d_in[7];
  const float* Whh   = (const float*)d_in[8];
  const float* bih   = (const float*)d_in[9];
  const float* bhh   = (const float*)d_in[10];
  const float* w1    = (const float*)d_in[11];
  const float* b1    = (const float*)d_in[12];
  float* out = (float*)d_out;

  char* ws = (char*)d_ws;
  size_t off = 0;
  auto alloc = [&](size_t bytes) -> void* {
    void* p = ws + off;
    off = (off + bytes + 255) & ~(size_t)255;
    return p;
  };
  unsigned short* wb   = (unsigned short*)alloc((size_t)NPAD * 256 * 2);  // 25.6 MB
  unsigned int*   act  = (unsigned int*)alloc((size_t)1280 * 128 * 4);    // 0.66 MB
  float*          gi   = (float*)alloc((size_t)NTOK * 384 * 4);           // 21.6 MB
  float*          outh = (float*)alloc((size_t)NTOK * 128 * 4);           // 7.2 MB
  float*          simr = (float*)alloc((size_t)12800 * 4);
  float*          sess = (float*)alloc((size_t)640 * 128 * 4);
  int*            cnt  = (int*)alloc(64 * 4);

  k12<<<K2BLOCKS + K1BLOCKS, 384, 0, stream>>>(w1, wb, cur, frd, vemb, Wih, bih, gi, cnt);
  k3_gru<<<(NSEQ + 2) / 3, 384, 0, stream>>>(Whh, bhh, gi, outh);
  k46f<<<640, 256, 0, stream>>>(users, frd, vemb, uemb, outh, simr, sess, cnt,
                                (unsigned int*)act);
  k9_gemm<<<(NPAD / 128) * 2, 256, 0, stream>>>((const unsigned short*)act, wb, b1, out);
}

// Round 6
// 522.472 us; speedup vs baseline: 1.1301x; 1.1301x over previous
//
#include <hip/hip_runtime.h>
#include <cstdint>
#include <cstddef>

#define H_      128
#define B_      64
#define T_      20
#define S_      10
#define L_      20
#define NITEMS  50000
#define NSEQ    704            // 64 cur + 640 frd sequences, all length 20
#define NTOK    (NSEQ * 20)    // 14080
#define NPAD    50048          // items padded to multiple of 128 for GEMM tiles
#define KA      256            // effective K of final GEMM (skip zero middle)

typedef __attribute__((ext_vector_type(8))) short short8;
typedef __attribute__((ext_vector_type(4))) float f32x4;

__device__ __forceinline__ unsigned short f2bf(float f) {
  unsigned int u = __float_as_uint(f);
  u += 0x7FFF + ((u >> 16) & 1);   // round-to-nearest-even
  return (unsigned short)(u >> 16);
}
__device__ __forceinline__ float sigmoidf_(float x) {
  return 1.0f / (1.0f + __expf(-x));
}

// ---------------------------------------------------------------------------
// K1: out1_w (50000 x 384 fp32) -> wb (50048 x 256 bf16), dropping cols 128..255
// (they multiply the zero hu block). Pad rows zeroed.
__global__ void __launch_bounds__(256) k1_convert_w(const float* __restrict__ w,
                                                    unsigned short* __restrict__ wb) {
  int t = blockIdx.x * 256 + threadIdx.x;   // NPAD*32 threads
  int n = t >> 5, kc = t & 31;
  int k0 = kc * 8;
  unsigned int o0, o1, o2, o3;
  if (n < NITEMS) {
    int src = (k0 < 128) ? k0 : (k0 + 128);
    const float* p = w + (size_t)n * 384 + src;
    float4 f0 = *(const float4*)p;
    float4 f1 = *(const float4*)(p + 4);
    o0 = (unsigned)f2bf(f0.x) | ((unsigned)f2bf(f0.y) << 16);
    o1 = (unsigned)f2bf(f0.z) | ((unsigned)f2bf(f0.w) << 16);
    o2 = (unsigned)f2bf(f1.x) | ((unsigned)f2bf(f1.y) << 16);
    o3 = (unsigned)f2bf(f1.z) | ((unsigned)f2bf(f1.w) << 16);
  } else {
    o0 = o1 = o2 = o3 = 0u;
  }
  *(uint4*)(wb + (size_t)n * 256 + k0) = make_uint4(o0, o1, o2, o3);
}

// ---------------------------------------------------------------------------
// K2: gi[token][384] = v_emb[id] @ W_ih^T + b_ih for all 14080 tokens (fp32).
// 16 tokens per block; thread j owns gate j for all 16 tokens.
__global__ void __launch_bounds__(384) k2_gi(const int* __restrict__ cur,
                                             const int* __restrict__ frd,
                                             const float* __restrict__ vemb,
                                             const float* __restrict__ Wih,
                                             const float* __restrict__ bih,
                                             float* __restrict__ gi) {
  __shared__ float xs[16 * 128];
  __shared__ int ids[16];
  int tid = threadIdx.x;
  int tok0 = blockIdx.x * 16;
  if (tid < 16) {
    int tok = tok0 + tid;
    int seq = tok / 20, tt = tok % 20;
    ids[tid] = (seq < 64) ? cur[seq * 20 + tt] : frd[(seq - 64) * 20 + tt];
  }
  __syncthreads();
  for (int idx = tid; idx < 512; idx += 384) {
    int i = idx >> 5, kc = idx & 31;
    *(float4*)&xs[i * 128 + kc * 4] =
        *(const float4*)&vemb[(size_t)ids[i] * 128 + kc * 4];
  }
  __syncthreads();
  int j = tid;  // 0..383
  float acc[16];
#pragma unroll
  for (int i = 0; i < 16; i++) acc[i] = 0.f;
  const float* wrow = Wih + (size_t)j * 128;
  for (int kc = 0; kc < 32; kc++) {
    float4 w4 = *(const float4*)(wrow + kc * 4);
#pragma unroll
    for (int i = 0; i < 16; i++) {
      float4 x4 = *(const float4*)&xs[i * 128 + kc * 4];
      acc[i] += w4.x * x4.x + w4.y * x4.y + w4.z * x4.z + w4.w * x4.w;
    }
  }
  float bb = bih[j];
#pragma unroll
  for (int i = 0; i < 16; i++)
    gi[(size_t)(tok0 + i) * 384 + j] = acc[i] + bb;
}

// ---------------------------------------------------------------------------
// K3: GRU recurrence, fp32. Thread j keeps W_hh row j (128 fp32) in registers;
// h broadcast from LDS. 3 sequences per block.
__global__ void __launch_bounds__(384) k3_gru(const float* __restrict__ Whh,
                                              const float* __restrict__ bhh,
                                              const float* __restrict__ gi,
                                              float* __restrict__ out_h) {
  __shared__ float hb[3 * 128];
  __shared__ float pre[3 * 256];
  __shared__ float gin[3 * 128];
  __shared__ float ghn[3 * 128];
  int j = threadIdx.x;
  int seq0 = blockIdx.x * 3;
  int G = NSEQ - seq0; if (G > 3) G = 3;
  float4 wv[32];
  const float4* wr = (const float4*)(Whh + (size_t)j * 128);
#pragma unroll
  for (int kc = 0; kc < 32; kc++) wv[kc] = wr[kc];
  float bb = bhh[j];
  if (j < 128) { hb[j] = 0.f; hb[128 + j] = 0.f; hb[256 + j] = 0.f; }
  __syncthreads();
  for (int t = 0; t < 20; t++) {
    for (int g = 0; g < G; g++) {
      float acc = bb;  // gh_j = W_hh[j] . h + b_hh[j]
#pragma unroll
      for (int kc = 0; kc < 32; kc++) {
        float4 h4 = *(const float4*)&hb[g * 128 + kc * 4];
        float4 w4 = wv[kc];
        acc += w4.x * h4.x + w4.y * h4.y + w4.z * h4.z + w4.w * h4.w;
      }
      float gv = gi[(size_t)((seq0 + g) * 20 + t) * 384 + j];
      if (j < 256) pre[g * 256 + j] = gv + acc;
      else { gin[g * 128 + (j - 256)] = gv; ghn[g * 128 + (j - 256)] = acc; }
    }
    __syncthreads();
    if (j < 128) {
      for (int g = 0; g < G; g++) {
        float r = sigmoidf_(pre[g * 256 + j]);
        float z = sigmoidf_(pre[g * 256 + 128 + j]);
        float n = tanhf(gin[g * 128 + j] + r * ghn[g * 128 + j]);
        float hN = (1.f - z) * n + z * hb[g * 128 + j];
        hb[g * 128 + j] = hN;
        out_h[(size_t)((seq0 + g) * 20 + t) * 128 + j] = hN;
      }
    }
    __syncthreads();
  }
}

// ---------------------------------------------------------------------------
// K4: sim_raw[b][s][t] = max_l hs[b][t] . enc[b][s][l]
__global__ void __launch_bounds__(256) k4_scores(const float* __restrict__ out_h,
                                                 float* __restrict__ sim_raw) {
  __shared__ float qs[20 * 132];
  __shared__ float es[20 * 132];
  __shared__ float sc[400];
  int tid = threadIdx.x;
  int b = blockIdx.x / 10, s = blockIdx.x % 10;
  int eseq = 64 + b * 10 + s;
  for (int idx = tid; idx < 640; idx += 256) {
    int row = idx >> 5, kc = idx & 31;
    *(float4*)&qs[row * 132 + kc * 4] =
        *(const float4*)&out_h[(size_t)(b * 20 + row) * 128 + kc * 4];
    *(float4*)&es[row * 132 + kc * 4] =
        *(const float4*)&out_h[(size_t)(eseq * 20 + row) * 128 + kc * 4];
  }
  __syncthreads();
  for (int idx = tid; idx < 400; idx += 256) {
    int t = idx / 20, l = idx % 20;
    float acc = 0.f;
#pragma unroll
    for (int kc = 0; kc < 32; kc++) {
      float4 q4 = *(const float4*)&qs[t * 132 + kc * 4];
      float4 e4 = *(const float4*)&es[l * 132 + kc * 4];
      acc += q4.x * e4.x + q4.y * e4.y + q4.z * e4.z + q4.w * e4.w;
    }
    sc[idx] = acc;
  }
  __syncthreads();
  if (tid < 20) {
    float m = sc[tid * 20];
    for (int l = 1; l < 20; l++) m = fmaxf(m, sc[tid * 20 + l]);
    sim_raw[(size_t)(b * 10 + s) * 20 + tid] = m;
  }
}

// ---------------------------------------------------------------------------
// K5: per-b: softmax over s -> sim1; top2 per t -> preserve; double masked
// softmax over s; zero masked -> sfin[b][s][t]
__global__ void __launch_bounds__(64) k5_soft(const float* __restrict__ sim_raw,
                                              float* __restrict__ sfin) {
  __shared__ float sv[200];
  __shared__ float s1[200];
  __shared__ int pres[10];
  int tid = threadIdx.x;
  int b = blockIdx.x;
  for (int idx = tid; idx < 200; idx += 64) sv[idx] = sim_raw[(size_t)b * 200 + idx];
  if (tid < 10) pres[tid] = 0;
  __syncthreads();
  if (tid < 20) {
    int t = tid;
    float mx = -3.4e38f;
    for (int s = 0; s < 10; s++) mx = fmaxf(mx, sv[s * 20 + t]);
    float sum = 0.f;
    for (int s = 0; s < 10; s++) sum += __expf(sv[s * 20 + t] - mx);
    float inv = 1.0f / sum;
    float v1 = -1.f, v2 = -1.f; int i1 = 0, i2 = 0;
    for (int s = 0; s < 10; s++) {
      float v = __expf(sv[s * 20 + t] - mx) * inv;
      s1[s * 20 + t] = v;
      if (v > v1) { v2 = v1; i2 = i1; v1 = v; i1 = s; }
      else if (v > v2) { v2 = v; i2 = s; }
    }
    atomicOr(&pres[i1], 1);
    atomicOr(&pres[i2], 1);
  }
  __syncthreads();
  if (tid < 20) {
    int t = tid;
    // first masked softmax over preserved s
    float mx = -3.4e38f;
    for (int s = 0; s < 10; s++) if (pres[s]) mx = fmaxf(mx, s1[s * 20 + t]);
    float sum = 0.f;
    for (int s = 0; s < 10; s++) if (pres[s]) sum += __expf(s1[s * 20 + t] - mx);
    float inv = 1.f / sum;
    // second masked softmax over the first's outputs
    float mx2 = -3.4e38f;
    for (int s = 0; s < 10; s++)
      if (pres[s]) mx2 = fmaxf(mx2, __expf(s1[s * 20 + t] - mx) * inv);
    float sum2 = 0.f;
    for (int s = 0; s < 10; s++)
      if (pres[s]) sum2 += __expf(__expf(s1[s * 20 + t] - mx) * inv - mx2);
    float inv2 = 1.f / sum2;
    for (int s = 0; s < 10; s++) {
      float o = 0.f;
      if (pres[s]) o = __expf(__expf(s1[s * 20 + t] - mx) * inv - mx2) * inv2;
      sfin[(size_t)(b * 10 + s) * 20 + t] = o;
    }
  }
}

// ---------------------------------------------------------------------------
// K6: user attention -> sess_emb[b][s][h]
__global__ void __launch_bounds__(128) k6_sess(const int* __restrict__ users,
                                               const int* __restrict__ frd,
                                               const float* __restrict__ vemb,
                                               const float* __restrict__ uemb,
                                               float* __restrict__ sess) {
  __shared__ float fs[20 * 132];
  __shared__ float us[128];
  __shared__ float dt[20];
  __shared__ float wl[20];
  __shared__ int fid[20];
  int tid = threadIdx.x;
  int b = blockIdx.x / 10, s = blockIdx.x % 10;
  if (tid < 20) fid[tid] = frd[(size_t)(b * 10 + s) * 20 + tid];
  us[tid] = uemb[(size_t)users[b] * 128 + tid];
  __syncthreads();
  for (int idx = tid; idx < 640; idx += 128) {
    int row = idx >> 5, kc = idx & 31;
    *(float4*)&fs[row * 132 + kc * 4] =
        *(const float4*)&vemb[(size_t)fid[row] * 128 + kc * 4];
  }
  __syncthreads();
  if (tid < 20) {
    float acc = 0.f;
    for (int kc = 0; kc < 32; kc++) {
      float4 u4 = *(const float4*)&us[kc * 4];
      float4 f4 = *(const float4*)&fs[tid * 132 + kc * 4];
      acc += u4.x * f4.x + u4.y * f4.y + u4.z * f4.z + u4.w * f4.w;
    }
    dt[tid] = acc;
  }
  __syncthreads();
  if (tid < 20) {
    float mx = -3.4e38f;
    for (int l = 0; l < 20; l++) mx = fmaxf(mx, dt[l]);
    float sum = 0.f;
    for (int l = 0; l < 20; l++) sum += __expf(dt[l] - mx);
    wl[tid] = __expf(dt[tid] - mx) / sum;
  }
  __syncthreads();
  float acc = 0.f;
  for (int l = 0; l < 20; l++) acc += wl[l] * fs[l * 132 + tid];
  sess[(size_t)(b * 10 + s) * 128 + tid] = acc;
}

// ---------------------------------------------------------------------------
// K7: hf[b][t][h] = sum_s sfin[b][s][t] * sess_emb[b][s][h]
__global__ void __launch_bounds__(256) k7_hf(const float* __restrict__ sfin,
                                             const float* __restrict__ sess,
                                             float* __restrict__ hf) {
  __shared__ float sf[200];
  __shared__ float se[10 * 128];
  int tid = threadIdx.x;
  int b = blockIdx.x;
  for (int idx = tid; idx < 200; idx += 256) sf[idx] = sfin[(size_t)b * 200 + idx];
  for (int idx = tid; idx < 1280; idx += 256) se[idx] = sess[(size_t)b * 1280 + idx];
  __syncthreads();
  for (int idx = tid; idx < 2560; idx += 256) {
    int t = idx >> 7, h = idx & 127;
    float acc = 0.f;
#pragma unroll
    for (int s = 0; s < 10; s++) acc += sf[s * 20 + t] * se[s * 128 + h];
    hf[(size_t)b * 2560 + idx] = acc;
  }
}

// ---------------------------------------------------------------------------
// K8: act[1280][256] bf16 = [hs | hf] per row m = b*20+t
__global__ void __launch_bounds__(256) k8_act(const float* __restrict__ out_h,
                                              const float* __restrict__ hf,
                                              unsigned int* __restrict__ act) {
  int g = blockIdx.x * 256 + threadIdx.x;  // 1280*128
  int m = g >> 7, p = g & 127;
  float a0, a1;
  if (p < 64) {
    a0 = out_h[(size_t)m * 128 + p * 2];
    a1 = out_h[(size_t)m * 128 + p * 2 + 1];
  } else {
    a0 = hf[(size_t)m * 128 + (p - 64) * 2];
    a1 = hf[(size_t)m * 128 + (p - 64) * 2 + 1];
  }
  act[g] = (unsigned)f2bf(a0) | ((unsigned)f2bf(a1) << 16);
}

// ---------------------------------------------------------------------------
// K9: logits[1280][50000] = act(bf16) @ wb^T + b.  m97-style: 128x128 block
// tile, B tile (128n x 256k) resident in LDS via global_load_lds with XOR-32
// swizzle; A streamed in K=32 slices through padded LDS; 4 waves, each with a
// 4x4 grid of 16x16x32 MFMA tiles.
__device__ __forceinline__ void async_cp16(const unsigned short* g, unsigned short* l) {
  __builtin_amdgcn_global_load_lds((__attribute__((address_space(1))) void*)g,
                                   (__attribute__((address_space(3))) void*)l,
                                   16, 0, 0);
}

__global__ void __launch_bounds__(256) k9_gemm(const unsigned short* __restrict__ act,
                                               const unsigned short* __restrict__ wb,
                                               const float* __restrict__ bias,
                                               float* __restrict__ out) {
  __shared__ __align__(16) unsigned short Bs[128 * 256];      // 64 KB, xor-swizzled
  __shared__ __align__(16) unsigned short As[128 * 40];       // 10 KB, padded rows (5 chunks)
  int tid = threadIdx.x;
  int w = tid >> 6, lane = tid & 63;
  int q = (lane >> 4) & 3, c = lane & 15;
  int wm = w >> 1, wn = w & 1;
  int nb0 = blockIdx.x * 128;

  // stage full B tile once: rows n_l = 0..127, 32 chunks (16B) per row
#pragma unroll
  for (int i = 0; i < 16; i++) {
    int n_l = i * 8 + w * 2 + (lane >> 5);
    int p = lane & 31;
    int kc = p ^ (n_l & 31);
    async_cp16(wb + (size_t)(nb0 + n_l) * 256 + kc * 8,
               &Bs[(i * 8 + w * 2) * 256]);
  }

  // bias + bounds per nt (hoisted)
  float bs[4]; int okn[4]; int ncol[4];
#pragma unroll
  for (int nt = 0; nt < 4; nt++) {
    int n = nb0 + wn * 64 + nt * 16 + c;
    ncol[nt] = n;
    okn[nt] = (n < NITEMS);
    bs[nt] = (n < NITEMS) ? bias[n] : 0.f;
  }

  for (int mc = 0; mc < 10; mc++) {
    f32x4 acc[4][4];
#pragma unroll
    for (int mt = 0; mt < 4; mt++)
#pragma unroll
      for (int nt = 0; nt < 4; nt++) {
        f32x4 z = {0.f, 0.f, 0.f, 0.f};
        acc[mt][nt] = z;
      }
    for (int kf = 0; kf < 8; kf++) {
      __syncthreads();  // previous slice consumed (and B-DMA drained on 1st pass)
      // stage A slice: 128 rows x 32 k (bf16), padded to 5 chunks/row
      {
        int ch0 = tid * 2;
#pragma unroll
        for (int jj = 0; jj < 2; jj++) {
          int ch = ch0 + jj;
          int row = ch >> 2, kk = ch & 3;
          short8 v = *(const short8*)&act[(size_t)(mc * 128 + row) * 256 + kf * 32 + kk * 8];
          *(short8*)&As[row * 40 + kk * 8] = v;
        }
      }
      __syncthreads();
      short8 bfr[4];
#pragma unroll
      for (int nt = 0; nt < 4; nt++) {
        int n_l = wn * 64 + nt * 16 + c;
        int slot = n_l * 32 + ((kf * 4 + q) ^ (n_l & 31));
        bfr[nt] = *(const short8*)&Bs[slot * 8];
      }
#pragma unroll
      for (int mt = 0; mt < 4; mt++) {
        int row = wm * 64 + mt * 16 + c;
        short8 af = *(const short8*)&As[row * 40 + q * 8];
#pragma unroll
        for (int nt = 0; nt < 4; nt++)
          acc[mt][nt] = __builtin_amdgcn_mfma_f32_16x16x32_bf16(af, bfr[nt], acc[mt][nt], 0, 0, 0);
      }
    }
    // epilogue: D row = q*4+r, col = c (C/D layout: col=lane&15, row=quad*4+reg)
#pragma unroll
    for (int nt = 0; nt < 4; nt++) {
      if (okn[nt]) {
#pragma unroll
        for (int mt = 0; mt < 4; mt++) {
          int m = mc * 128 + wm * 64 + mt * 16 + q * 4;
#pragma unroll
          for (int r = 0; r < 4; r++)
            out[(size_t)(m + r) * NITEMS + ncol[nt]] = acc[mt][nt][r] + bs[nt];
        }
      }
    }
  }
}

// ---------------------------------------------------------------------------
extern "C" void kernel_launch(void* const* d_in, const int* in_sizes, int n_in,
                              void* d_out, int out_size, void* d_ws, size_t ws_size,
                              hipStream_t stream) {
  const int*   users = (const int*)d_in[0];
  const int*   cur   = (const int*)d_in[1];
  // d_in[2] = hist_sess (unused by reference)
  const int*   frd   = (const int*)d_in[3];
  // d_in[4] = cur_sess_len (unused by reference)
  const float* vemb  = (const float*)d_in[5];
  const float* uemb  = (const float*)d_in[6];
  const float* Wih   = (const float*)d_in[7];
  const float* Whh   = (const float*)d_in[8];
  const float* bih   = (const float*)d_in[9];
  const float* bhh   = (const float*)d_in[10];
  const float* w1    = (const float*)d_in[11];
  const float* b1    = (const float*)d_in[12];
  float* out = (float*)d_out;

  char* ws = (char*)d_ws;
  size_t off = 0;
  auto alloc = [&](size_t bytes) -> void* {
    void* p = ws + off;
    off = (off + bytes + 255) & ~(size_t)255;
    return p;
  };
  unsigned short* wb   = (unsigned short*)alloc((size_t)NPAD * 256 * 2);  // 25.6 MB
  unsigned int*   act  = (unsigned int*)alloc((size_t)1280 * 128 * 4);    // 0.66 MB
  float*          gi   = (float*)alloc((size_t)NTOK * 384 * 4);           // 21.6 MB
  float*          outh = (float*)alloc((size_t)NTOK * 128 * 4);           // 7.2 MB
  float*          simr = (float*)alloc((size_t)12800 * 4);
  float*          sfin = (float*)alloc((size_t)12800 * 4);
  float*          sess = (float*)alloc((size_t)640 * 128 * 4);
  float*          hf   = (float*)alloc((size_t)1280 * 128 * 4);

  k1_convert_w<<<NPAD / 8, 256, 0, stream>>>(w1, wb);
  k2_gi<<<NTOK / 16, 384, 0, stream>>>(cur, frd, vemb, Wih, bih, gi);
  k3_gru<<<(NSEQ + 2) / 3, 384, 0, stream>>>(Whh, bhh, gi, outh);
  k4_scores<<<640, 256, 0, stream>>>(outh, simr);
  k5_soft<<<64, 64, 0, stream>>>(simr, sfin);
  k6_sess<<<640, 128, 0, stream>>>(users, frd, vemb, uemb, sess);
  k7_hf<<<64, 256, 0, stream>>>(sfin, sess, hf);
  k8_act<<<640, 256, 0, stream>>>(outh, hf, act);
  k9_gemm<<<NPAD / 128, 256, 0, stream>>>((const unsigned short*)act, wb, b1, out);
}